// Round 5
// baseline (129.714 us; speedup 1.0000x reference)
//
#include <hip/hip_runtime.h>

#define NPTS 1024
#define NA   60
#define CIN  64
#define KSZ  3
#define ANN  8
#define COUT 128
#define KD   192   // i' = k_s*64 + c, 6 k-tiles of 32

using bf16x8 = __attribute__((ext_vector_type(8))) short;
using f32x4  = __attribute__((ext_vector_type(4))) float;

__device__ __forceinline__ unsigned short f2bf(float f) {
    unsigned int u = __builtin_bit_cast(unsigned int, f);
    u += 0x7FFFu + ((u >> 16) & 1u);          // RNE
    return (unsigned short)(u >> 16);
}

// d_ws layout (shorts):
//   [0      .. 24576)  W_frag[mt=8][kt=6][lane=64][j=8]   (A-frag layout)
//   [24576  .. 36864)  S_frag[nt=12][kt=2][lane=64][j=8]  (B-frag layout)
//   [36864  .. +2048*12288)  As dump: per point bp, Bfrag[kt=6][nt=4][lane=64][j=8]

// ---------------- pre-kernel: build W_frag + S_frag ----------------
__global__ void build_tables(const float* __restrict__ intra_w,
                             const float* __restrict__ W,
                             const int*   __restrict__ intra_idx,
                             unsigned short* __restrict__ ws) {
    int f = blockIdx.x * 256 + threadIdx.x;
    if (f < 24576) {
        int j = f & 7, l = (f >> 3) & 63, x = f >> 9;
        int kt = x % 6, mt = x / 6;
        int m  = mt * 16 + (l & 15);
        int ip = kt * 32 + 8 * (l >> 4) + j;      // i'
        int c  = ip & 63, ks = ip >> 6;
        ws[f] = f2bf(W[m * KD + c * KSZ + ks]);
    } else if (f < 36864) {
        int f2 = f - 24576;
        int j = f2 & 7, l = (f2 >> 3) & 63;
        int kt = (f2 >> 9) & 1, nt = f2 >> 10;
        int np = nt * 16 + (l & 15);              // n' = ks*60+o
        int ap = kt * 32 + 8 * (l >> 4) + j;      // a'
        float s = 0.f;
        if (np < 180 && ap < 60) {
            int ks = (np >= 120) ? 2 : ((np >= 60) ? 1 : 0);
            int o  = np - 60 * ks;
            const int*   ix = intra_idx + (o * KSZ + ks) * ANN;
            const float* wx = intra_w   + (o * KSZ + ks) * ANN;
            #pragma unroll
            for (int a = 0; a < ANN; a++) s += (ix[a] == ap) ? wx[a] : 0.f;
        }
        ws[f] = f2bf(s);
    }
}

// ---------------- kernel A: GEMM-1 + transpose + coalesced As dump ----------------
__global__ __launch_bounds__(256, 4)
void intrazp_gather(const float* __restrict__ feats,
                    unsigned short* __restrict__ ws) {
    // fsS[c=64][a=64] bf16, swizzled:  byte(c,a) = (c*128 + a*2) ^ ((c&7)<<4)
    // AsT[o=64][i'=192] bf16, swizzled: byte(o,i') = (o*384 + i'*2) ^ ((o&7)<<4)
    __shared__ __align__(16) unsigned short fsS[64 * 64];
    __shared__ __align__(16) unsigned short AsT[64 * 192];

    const int t    = threadIdx.x;
    const int wave = t >> 6, lane = t & 63;
    const int l15  = lane & 15, g = lane >> 4;
    const int bid  = blockIdx.x;
    const int bp   = (bid & 7) * 256 + (bid >> 3);   // bijective XCD swizzle (2048%8==0)
    const int b    = bp >> 10, p = bp & 1023;

    // ---- stage feats[b,:,p,:] into fsS (coalesced float4, bf16 cvt) ----
    {
        const float* fb = feats + (size_t)b * CIN * NPTS * NA + (size_t)p * NA;
        #pragma unroll
        for (int r = 0; r < 4; r++) {
            int q = t + r * 256;                  // 15 float4 chunks per c-row
            if (q < 960) {
                int c = q / 15, w = q - c * 15;
                float4 v = *(const float4*)(fb + (size_t)c * NPTS * NA + w * 4);
                unsigned int lo = (unsigned int)f2bf(v.x) | ((unsigned int)f2bf(v.y) << 16);
                unsigned int hi = (unsigned int)f2bf(v.z) | ((unsigned int)f2bf(v.w) << 16);
                int byte = (c * 128 + w * 8) ^ ((c & 7) << 4);
                *(uint2*)((char*)fsS + byte) = make_uint2(lo, hi);
            }
        }
        if (t < 64) {   // zero-pad a = 60..63
            int byte = (t * 128 + 120) ^ ((t & 7) << 4);
            *(uint2*)((char*)fsS + byte) = make_uint2(0u, 0u);
        }
        if (t < 192) {  // zero-pad AsT rows o = 60..63
            *(uint2*)((char*)AsT + 60 * 384 + t * 8) = make_uint2(0u, 0u);
        }
    }
    __syncthreads();

    // ---- GEMM-1: G[c][(ks,o)] = fs(64x60) * S(60x180) ----
    const unsigned short* Sfrag = ws + 24576;
    const int wm = wave & 1, wn = wave >> 1;

    bf16x8 a1[2][2];
    #pragma unroll
    for (int mi = 0; mi < 2; mi++) {
        int c = (2 * wm + mi) * 16 + l15;
        #pragma unroll
        for (int kt = 0; kt < 2; kt++) {
            int byte = (c * 128 + kt * 64 + g * 16) ^ ((c & 7) << 4);
            a1[mi][kt] = *(const bf16x8*)((char*)fsS + byte);
        }
    }

    #pragma unroll
    for (int ni = 0; ni < 6; ni++) {
        int nt = wn * 6 + ni;
        bf16x8 b0 = *(const bf16x8*)(Sfrag + ((nt * 2 + 0) * 64 + lane) * 8);
        bf16x8 b1 = *(const bf16x8*)(Sfrag + ((nt * 2 + 1) * 64 + lane) * 8);

        int np = nt * 16 + l15;                    // n' = ks*60 + o
        int ks = (np >= 120) ? 2 : ((np >= 60) ? 1 : 0);
        int o  = np - 60 * ks;
        int sw = (o & 7) << 4;
        int rowbyte = o * 384;

        #pragma unroll
        for (int mi = 0; mi < 2; mi++) {
            f32x4 acc = {0.f, 0.f, 0.f, 0.f};
            acc = __builtin_amdgcn_mfma_f32_16x16x32_bf16(a1[mi][0], b0, acc, 0, 0, 0);
            acc = __builtin_amdgcn_mfma_f32_16x16x32_bf16(a1[mi][1], b1, acc, 0, 0, 0);
            if (np < 180) {
                int cbase = (2 * wm + mi) * 16 + 4 * g;
                int ipb   = ks * 64 + cbase;       // i' rows consecutive
                unsigned int lo = (unsigned int)f2bf(acc[0]) | ((unsigned int)f2bf(acc[1]) << 16);
                unsigned int hi = (unsigned int)f2bf(acc[2]) | ((unsigned int)f2bf(acc[3]) << 16);
                int byte = (rowbyte + ipb * 2) ^ sw;
                *(uint2*)((char*)AsT + byte) = make_uint2(lo, hi);
            }
        }
    }

    __syncthreads();

    // ---- dump AsT to global in kernel-B's B-frag order (coalesced 16B/lane) ----
    unsigned short* AsD = ws + 36864 + (size_t)bp * 12288;
    #pragma unroll
    for (int r = 0; r < 6; r++) {
        int q  = t + r * 256;                  // 0..1535
        int l  = q & 63, ntkt = q >> 6;
        int nt = ntkt & 3, kt = ntkt >> 2;
        int o  = nt * 16 + (l & 15);
        int col = kt * 32 + 8 * (l >> 4);
        int byte = (o * 384 + col * 2) ^ ((o & 7) << 4);
        *(bf16x8*)(AsD + (size_t)q * 8) = *(const bf16x8*)((char*)AsT + byte);
    }
}

// ---------------- kernel B: pure streaming GEMM, one wave per point ----------------
__global__ __launch_bounds__(256, 2)
void intrazp_conv(const unsigned short* __restrict__ ws,
                  const float* __restrict__ bias,
                  float* __restrict__ out) {
    const int t    = threadIdx.x;
    const int wave = t >> 6, lane = t & 63;
    const int l15  = lane & 15, g = lane >> 4;
    const int bid  = blockIdx.x;                    // 512 blocks
    const int blk  = (bid & 7) * 64 + (bid >> 3);   // bijective XCD swizzle (512%8==0)
    const int bp   = blk * 4 + wave;                // one point per wave
    const int b    = bp >> 10, p = bp & 1023;

    const unsigned short* Bf = ws + 36864 + (size_t)bp * 12288;

    f32x4 acc[8][4];
    #pragma unroll
    for (int mt = 0; mt < 8; mt++)
        #pragma unroll
        for (int nt = 0; nt < 4; nt++) acc[mt][nt] = (f32x4){0.f, 0.f, 0.f, 0.f};

    #pragma unroll
    for (int kt = 0; kt < 6; kt++) {
        bf16x8 bb[4];
        #pragma unroll
        for (int nt = 0; nt < 4; nt++)
            bb[nt] = *(const bf16x8*)(Bf + ((size_t)(kt * 4 + nt) * 64 + lane) * 8);
        #pragma unroll
        for (int mt = 0; mt < 8; mt++) {
            bf16x8 a2 = *(const bf16x8*)(ws + ((size_t)(mt * 6 + kt) * 64 + lane) * 8);
            #pragma unroll
            for (int nt = 0; nt < 4; nt++)
                acc[mt][nt] = __builtin_amdgcn_mfma_f32_16x16x32_bf16(a2, bb[nt], acc[mt][nt], 0, 0, 0);
        }
    }

    // epilogue: out[b, co, p, o] = acc + bias
    #pragma unroll
    for (int mt = 0; mt < 8; mt++) {
        int cbase = mt * 16 + 4 * g;
        float4 bv = *(const float4*)(bias + cbase);
        float* ob = out + (((size_t)b * COUT + cbase) * NPTS + p) * NA;
        const size_t cs = (size_t)NPTS * NA;
        #pragma unroll
        for (int nt = 0; nt < 4; nt++) {
            int o = nt * 16 + l15;
            if (o < NA) {
                ob[0 * cs + o] = acc[mt][nt][0] + bv.x;
                ob[1 * cs + o] = acc[mt][nt][1] + bv.y;
                ob[2 * cs + o] = acc[mt][nt][2] + bv.z;
                ob[3 * cs + o] = acc[mt][nt][3] + bv.w;
            }
        }
    }
}

extern "C" void kernel_launch(void* const* d_in, const int* in_sizes, int n_in,
                              void* d_out, int out_size, void* d_ws, size_t ws_size,
                              hipStream_t stream) {
    const float* feats     = (const float*)d_in[0];
    const float* intra_w   = (const float*)d_in[1];
    const float* W         = (const float*)d_in[2];
    const float* bias      = (const float*)d_in[3];
    const int*   intra_idx = (const int*)d_in[4];
    float* out = (float*)d_out;
    unsigned short* ws = (unsigned short*)d_ws;   // needs 73728 + 2048*24576 B ≈ 50.4 MB

    build_tables<<<dim3(144), dim3(256), 0, stream>>>(intra_w, W, intra_idx, ws);
    intrazp_gather<<<dim3(2 * NPTS), dim3(256), 0, stream>>>(feats, ws);
    intrazp_conv<<<dim3(512), dim3(256), 0, stream>>>(ws, bias, out);
}

// Round 7
// 105.172 us; speedup vs baseline: 1.2334x; 1.2334x over previous
//
#include <hip/hip_runtime.h>

#define NPTS 1024
#define NA   60
#define CIN  64
#define KSZ  3
#define ANN  8
#define COUT 128
#define KD   192   // i' = k_s*64 + c, 6 k-tiles of 32

using bf16x8 = __attribute__((ext_vector_type(8))) short;
using f32x4  = __attribute__((ext_vector_type(4))) float;

__device__ __forceinline__ unsigned short f2bf(float f) {
    unsigned int u = __builtin_bit_cast(unsigned int, f);
    u += 0x7FFFu + ((u >> 16) & 1u);          // RNE
    return (unsigned short)(u >> 16);
}

// d_ws layout (shorts):
//   [0      .. 24576)  W_frag[mt=8][kt=6][lane=64][j=8]   (A-frag layout)
//   [24576  .. 36864)  S_frag[nt=12][kt=2][lane=64][j=8]  (B-frag layout)
__global__ void build_tables(const float* __restrict__ intra_w,
                             const float* __restrict__ W,
                             const int*   __restrict__ intra_idx,
                             unsigned short* __restrict__ ws) {
    int f = blockIdx.x * 256 + threadIdx.x;
    if (f < 24576) {
        int j = f & 7, l = (f >> 3) & 63, x = f >> 9;
        int kt = x % 6, mt = x / 6;
        int m  = mt * 16 + (l & 15);
        int ip = kt * 32 + 8 * (l >> 4) + j;      // i'
        int c  = ip & 63, ks = ip >> 6;
        ws[f] = f2bf(W[m * KD + c * KSZ + ks]);
    } else if (f < 36864) {
        int f2 = f - 24576;
        int j = f2 & 7, l = (f2 >> 3) & 63;
        int kt = (f2 >> 9) & 1, nt = f2 >> 10;
        int np = nt * 16 + (l & 15);              // n' = ks*60+o
        int ap = kt * 32 + 8 * (l >> 4) + j;      // a'
        float s = 0.f;
        if (np < 180 && ap < 60) {
            int ks = (np >= 120) ? 2 : ((np >= 60) ? 1 : 0);
            int o  = np - 60 * ks;
            const int*   ix = intra_idx + (o * KSZ + ks) * ANN;
            const float* wx = intra_w   + (o * KSZ + ks) * ANN;
            #pragma unroll
            for (int a = 0; a < ANN; a++) s += (ix[a] == ap) ? wx[a] : 0.f;
        }
        ws[f] = f2bf(s);
    }
}

// ---------------- persistent kernel: 256 blocks (1/CU), 512 threads, 8 points each ----------------
// Two barriers per point, SINGLE AsT buffer: G1 -> bar -> G2 -> bar. Provably race-free
// (no runtime-indexed LDS aliasing; every read/write pair separated by a barrier).
__global__ __launch_bounds__(512, 2)
void intrazp_persist(const float* __restrict__ feats,
                     const float* __restrict__ bias,
                     const unsigned short* __restrict__ ws,
                     float* __restrict__ out) {
    // fsS2[c=64][pt=8][a=64] bf16, swizzled: byte = (c*1024 + pt*128 + a*2) ^ ((c&7)<<4)
    // AsT[o=64][i'=192] bf16, swizzled: byte = (o*384 + i'*2) ^ ((o&7)<<4)
    __shared__ __align__(16) unsigned short fsS2[64 * 8 * 64];     // 64 KB
    __shared__ __align__(16) unsigned short AsT[64 * 192];         // 24 KB

    const int t    = threadIdx.x;
    const int wave = t >> 6, lane = t & 63;
    const int l15  = lane & 15, g = lane >> 4;
    const int x    = blockIdx.x;                 // 256 blocks
    const int b    = x >> 7, pbase = (x & 127) * 8;

    // ---- role split ----
    const int wm  = wave & 1, wn = wave >> 1;    // GEMM-1: mtile-pair, ntile-triple
    const int h   = wave >> 2, nt2 = wave & 3;   // GEMM-2: mtile-quad half, ntile

    // ---- hoist constants (loaded ONCE per block, reused for 8 points) ----
    const unsigned short* Sfrag = ws + 24576;
    bf16x8 Sreg[3][2];
    #pragma unroll
    for (int ni = 0; ni < 3; ni++)
        #pragma unroll
        for (int kt = 0; kt < 2; kt++)
            Sreg[ni][kt] = *(const bf16x8*)(Sfrag + (((3 * wn + ni) * 2 + kt) * 64 + lane) * 8);

    bf16x8 Wreg[4][6];
    #pragma unroll
    for (int m = 0; m < 4; m++)
        #pragma unroll
        for (int kt = 0; kt < 6; kt++)
            Wreg[m][kt] = *(const bf16x8*)(ws + (((h * 4 + m) * 6 + kt) * 64 + lane) * 8);

    float4 bvv[4];
    #pragma unroll
    for (int m = 0; m < 4; m++)
        bvv[m] = *(const float4*)(bias + (h * 4 + m) * 16 + 4 * g);

    // ---- stage ALL 8 points' feats (coalesced float4 streams, bf16 cvt) ----
    {
        const float* fb = feats + (size_t)b * CIN * NPTS * NA + (size_t)pbase * NA;
        #pragma unroll
        for (int r = 0; r < 15; r++) {
            int gid = r * 512 + t;               // 0..7679
            int c  = gid / 120, u = gid - c * 120;
            int pt = u / 15,   w = u - pt * 15;
            float4 v = *(const float4*)(fb + (size_t)c * NPTS * NA + pt * NA + w * 4);
            unsigned int lo = (unsigned int)f2bf(v.x) | ((unsigned int)f2bf(v.y) << 16);
            unsigned int hi = (unsigned int)f2bf(v.z) | ((unsigned int)f2bf(v.w) << 16);
            int byte = (c * 1024 + pt * 128 + w * 8) ^ ((c & 7) << 4);
            *(uint2*)((char*)fsS2 + byte) = make_uint2(lo, hi);
        }
        {   // zero-pad a = 60..63 for every (c, pt)
            int c = t >> 3, pt = t & 7;
            int byte = (c * 1024 + pt * 128 + 120) ^ ((c & 7) << 4);
            *(uint2*)((char*)fsS2 + byte) = make_uint2(0u, 0u);
        }
        if (t < 192) {  // zero-pad AsT rows o=60..63 (written once, G1 never touches them)
            *(uint2*)((char*)AsT + 60 * 384 + t * 8) = make_uint2(0u, 0u);
        }
    }
    __syncthreads();

    // ---- per-point: G1 -> barrier -> G2 -> barrier ----
    for (int pt = 0; pt < 8; ++pt) {
        // GEMM-1: G[c][(ks,o)] = fs_pt(64x60) * S(60x180)
        bf16x8 a1[2][2];
        #pragma unroll
        for (int mi = 0; mi < 2; mi++) {
            int c = (wm * 2 + mi) * 16 + l15;
            #pragma unroll
            for (int kt = 0; kt < 2; kt++) {
                int byte = (c * 1024 + pt * 128 + kt * 64 + g * 16) ^ ((c & 7) << 4);
                a1[mi][kt] = *(const bf16x8*)((char*)fsS2 + byte);
            }
        }
        #pragma unroll
        for (int ni = 0; ni < 3; ni++) {
            int nt = 3 * wn + ni;
            int np = nt * 16 + l15;               // n' = ks*60 + o
            int ks = (np >= 120) ? 2 : ((np >= 60) ? 1 : 0);
            int o  = np - 60 * ks;
            int sw = (o & 7) << 4;
            int rowbyte = o * 384;
            #pragma unroll
            for (int mi = 0; mi < 2; mi++) {
                f32x4 acc1 = {0.f, 0.f, 0.f, 0.f};
                acc1 = __builtin_amdgcn_mfma_f32_16x16x32_bf16(a1[mi][0], Sreg[ni][0], acc1, 0, 0, 0);
                acc1 = __builtin_amdgcn_mfma_f32_16x16x32_bf16(a1[mi][1], Sreg[ni][1], acc1, 0, 0, 0);
                if (np < 180) {
                    int cbase = (wm * 2 + mi) * 16 + 4 * g;
                    int ipb   = ks * 64 + cbase;   // i' rows consecutive (cbase mult of 4)
                    unsigned int lo = (unsigned int)f2bf(acc1[0]) | ((unsigned int)f2bf(acc1[1]) << 16);
                    unsigned int hi = (unsigned int)f2bf(acc1[2]) | ((unsigned int)f2bf(acc1[3]) << 16);
                    int byte = (rowbyte + ipb * 2) ^ sw;
                    *(uint2*)((char*)AsT + byte) = make_uint2(lo, hi);
                }
            }
        }

        __syncthreads();   // AsT complete before any G2 read

        // GEMM-2: out[co][o] = W(128x192) * As(192x60) + bias
        int o   = nt2 * 16 + l15;
        int swo = (o & 7) << 4, rbo = o * 384;
        bf16x8 bb[6];
        #pragma unroll
        for (int kt = 0; kt < 6; kt++)
            bb[kt] = *(const bf16x8*)((char*)AsT + ((rbo + (kt * 32 + 8 * g) * 2) ^ swo));

        f32x4 acc[4];
        #pragma unroll
        for (int m = 0; m < 4; m++) acc[m] = (f32x4){0.f, 0.f, 0.f, 0.f};
        #pragma unroll
        for (int kt = 0; kt < 6; kt++)
            #pragma unroll
            for (int m = 0; m < 4; m++)
                acc[m] = __builtin_amdgcn_mfma_f32_16x16x32_bf16(Wreg[m][kt], bb[kt], acc[m], 0, 0, 0);

        // epilogue
        int p = pbase + pt;
        if (o < NA) {
            const size_t cs = (size_t)NPTS * NA;
            #pragma unroll
            for (int m = 0; m < 4; m++) {
                int cbase = (h * 4 + m) * 16 + 4 * g;
                float* ob = out + (((size_t)b * COUT + cbase) * NPTS + p) * NA + o;
                ob[0 * cs] = acc[m][0] + bvv[m].x;
                ob[1 * cs] = acc[m][1] + bvv[m].y;
                ob[2 * cs] = acc[m][2] + bvv[m].z;
                ob[3 * cs] = acc[m][3] + bvv[m].w;
            }
        }

        __syncthreads();   // all G2 reads done before next G1 overwrites AsT
    }
}

extern "C" void kernel_launch(void* const* d_in, const int* in_sizes, int n_in,
                              void* d_out, int out_size, void* d_ws, size_t ws_size,
                              hipStream_t stream) {
    const float* feats     = (const float*)d_in[0];
    const float* intra_w   = (const float*)d_in[1];
    const float* W         = (const float*)d_in[2];
    const float* bias      = (const float*)d_in[3];
    const int*   intra_idx = (const int*)d_in[4];
    float* out = (float*)d_out;
    unsigned short* ws = (unsigned short*)d_ws;   // needs 73728 B

    build_tables<<<dim3(144), dim3(256), 0, stream>>>(intra_w, W, intra_idx, ws);
    intrazp_persist<<<dim3(256), dim3(512), 0, stream>>>(feats, bias, ws, out);
}